// Round 1
// baseline (7562.002 us; speedup 1.0000x reference)
//
#include <hip/hip_runtime.h>
#include <hip/hip_bf16.h>
#include <cmath>

#define NNODES 100000
#define NGRAPHS 64

__device__ __forceinline__ void atomicMaxF(float* addr, float v) {
    if (v >= 0.f) atomicMax((int*)addr, __float_as_int(v));
    else          atomicMin((unsigned int*)addr, __float_as_uint(v));
}

__global__ void copy_kernel(float4* __restrict__ dst, const float4* __restrict__ src, int n4) {
    int i = blockIdx.x * blockDim.x + threadIdx.x;
    if (i < n4) dst[i] = src[i];
}

// pre[dst] += h[src] over all edges; D = 4<<LOGC floats per row
template<int LOGC>
__global__ void scatter_kernel(float* __restrict__ pre, const float* __restrict__ h,
                               const int* __restrict__ ei, int E) {
    const int C = 1 << LOGC;      // float4 chunks per row
    const int D = C * 4;
    int gid = blockIdx.x * blockDim.x + threadIdx.x;
    int e = gid >> LOGC;
    if (e >= E) return;
    int c = gid & (C - 1);
    int src = ei[e];
    int dst = ei[E + e];
    const float4 v = *(const float4*)(h + (size_t)src * D + c * 4);
    float* p = pre + (size_t)dst * D + c * 4;
    unsafeAtomicAdd(p + 0, v.x);
    unsafeAtomicAdd(p + 1, v.y);
    unsafeAtomicAdd(p + 2, v.z);
    unsafeAtomicAdd(p + 3, v.w);
}

// out[M x 128] = A[M x K] @ W[K x 128] + bias (optionally relu)
// block: 256 threads = 16 rows x 16 col-groups of 8
template<int K, bool RELU>
__global__ __launch_bounds__(256) void gemm_kernel(const float* __restrict__ A,
                                                   const float* __restrict__ W,
                                                   const float* __restrict__ bias,
                                                   float* __restrict__ out, int M) {
    __shared__ float wlds[64 * 128];
    __shared__ float alds[16 * K];
    const int tid = threadIdx.x;
    const int r0 = blockIdx.x * 16;

    // stage A tile (contiguous 16*K floats)
    {
        int nv = 16 * K;
        int rem = (M - r0) * K;
        if (rem < nv) nv = rem;
        const float4* Asrc = (const float4*)(A + (size_t)r0 * K);
        float4* Adst = (float4*)alds;
        for (int i = tid; i < nv / 4; i += 256) Adst[i] = Asrc[i];
    }

    const int row = tid >> 4;
    const int c0 = (tid & 15) * 8;
    float acc[8];
#pragma unroll
    for (int j = 0; j < 8; ++j) acc[j] = 0.f;

    for (int kp = 0; kp < K; kp += 64) {
        __syncthreads();
        const float4* Wsrc = (const float4*)(W + (size_t)kp * 128);
        for (int i = tid; i < (64 * 128) / 4; i += 256) ((float4*)wlds)[i] = Wsrc[i];
        __syncthreads();
#pragma unroll 8
        for (int k = 0; k < 64; ++k) {
            float a = alds[row * K + kp + k];
            const float* wrow = &wlds[k * 128 + c0];
#pragma unroll
            for (int j = 0; j < 8; ++j) acc[j] = fmaf(a, wrow[j], acc[j]);
        }
    }

    if (r0 + row < M) {
        float* orow = out + (size_t)(r0 + row) * 128 + c0;
        float4 v0, v1;
        float t[8];
#pragma unroll
        for (int j = 0; j < 8; ++j) {
            float v = acc[j] + bias[c0 + j];
            if (RELU) v = fmaxf(v, 0.f);
            t[j] = v;
        }
        v0 = make_float4(t[0], t[1], t[2], t[3]);
        v1 = make_float4(t[4], t[5], t[6], t[7]);
        *(float4*)(orow) = v0;
        *(float4*)(orow + 4) = v1;
    }
}

__global__ void init_pool_kernel(float* p) {
    int i = blockIdx.x * blockDim.x + threadIdx.x;
    if (i < NGRAPHS * 128) p[i] = -INFINITY;
}

// block: 128 threads (one per feature), each block scans 512 consecutive nodes
__global__ __launch_bounds__(128) void pool_kernel(float* __restrict__ pooled,
                                                   const float* __restrict__ h,
                                                   const int* __restrict__ batch, int N) {
    const int f = threadIdx.x;
    int n0 = blockIdx.x * 512;
    int n1 = n0 + 512;
    if (n1 > N) n1 = N;
    int cur = -1;
    float run = -INFINITY;
    for (int n = n0; n < n1; ++n) {
        int g = batch[n];
        if (g != cur) {
            if (cur >= 0) atomicMaxF(&pooled[cur * 128 + f], run);
            cur = g;
            run = -INFINITY;
        }
        run = fmaxf(run, h[(size_t)n * 128 + f]);
    }
    if (cur >= 0) atomicMaxF(&pooled[cur * 128 + f], run);
}

__global__ __launch_bounds__(64) void head_kernel(float* __restrict__ out,
                                                  const float* __restrict__ pooled,
                                                  const float* __restrict__ w1,
                                                  const float* __restrict__ b1,
                                                  const float* __restrict__ w2,
                                                  const float* __restrict__ b2) {
    int g = blockIdx.x, t = threadIdx.x;
    __shared__ float a[64];
    __shared__ float o[10];
    __shared__ float red[2];
    const float* pg = pooled + g * 128;
    float acc = b1[t];
    for (int k = 0; k < 128; ++k) acc = fmaf(pg[k], w1[k * 64 + t], acc);
    a[t] = fmaxf(acc, 0.f);
    __syncthreads();
    if (t < 10) {
        float s = b2[t];
        for (int k = 0; k < 64; ++k) s = fmaf(a[k], w2[k * 10 + t], s);
        o[t] = s;
    }
    __syncthreads();
    if (t == 0) {
        float m = -INFINITY;
        for (int c = 0; c < 10; ++c) m = fmaxf(m, o[c]);
        float se = 0.f;
        for (int c = 0; c < 10; ++c) se += expf(o[c] - m);
        red[0] = m;
        red[1] = logf(se);
    }
    __syncthreads();
    if (t < 10) out[g * 10 + t] = o[t] - red[0] - red[1];
}

extern "C" void kernel_launch(void* const* d_in, const int* in_sizes, int n_in,
                              void* d_out, int out_size, void* d_ws, size_t ws_size,
                              hipStream_t stream) {
    const float* x    = (const float*)d_in[0];
    const int* ei     = (const int*)d_in[1];
    const int* batch  = (const int*)d_in[2];
    const float* g1w1 = (const float*)d_in[3];  const float* g1b1 = (const float*)d_in[4];
    const float* g1w2 = (const float*)d_in[5];  const float* g1b2 = (const float*)d_in[6];
    const float* g2w1 = (const float*)d_in[7];  const float* g2b1 = (const float*)d_in[8];
    const float* g2w2 = (const float*)d_in[9];  const float* g2b2 = (const float*)d_in[10];
    const float* g3w1 = (const float*)d_in[11]; const float* g3b1 = (const float*)d_in[12];
    const float* g3w2 = (const float*)d_in[13]; const float* g3b2 = (const float*)d_in[14];
    const float* f1w  = (const float*)d_in[15]; const float* f1b  = (const float*)d_in[16];
    const float* f2w  = (const float*)d_in[17]; const float* f2b  = (const float*)d_in[18];
    float* out = (float*)d_out;

    const int N = NNODES;
    const int E = in_sizes[1] / 2;

    float* P = (float*)d_ws;
    float* Q = P + (size_t)N * 128;
    float* pooled = Q + (size_t)N * 128;

    // ---- layer 1 (input dim 64) ----
    copy_kernel<<<(N * 64 / 4 + 255) / 256, 256, 0, stream>>>((float4*)P, (const float4*)x, N * 64 / 4);
    scatter_kernel<4><<<(E * 16 + 255) / 256, 256, 0, stream>>>(P, x, ei, E);
    gemm_kernel<64, true><<<(N + 15) / 16, 256, 0, stream>>>(P, g1w1, g1b1, Q, N);
    gemm_kernel<128, false><<<(N + 15) / 16, 256, 0, stream>>>(Q, g1w2, g1b2, P, N);

    // ---- layer 2 ----
    copy_kernel<<<(N * 128 / 4 + 255) / 256, 256, 0, stream>>>((float4*)Q, (const float4*)P, N * 128 / 4);
    scatter_kernel<5><<<(E * 32 + 255) / 256, 256, 0, stream>>>(Q, P, ei, E);
    gemm_kernel<128, true><<<(N + 15) / 16, 256, 0, stream>>>(Q, g2w1, g2b1, P, N);
    gemm_kernel<128, false><<<(N + 15) / 16, 256, 0, stream>>>(P, g2w2, g2b2, Q, N);

    // ---- layer 3 ----
    copy_kernel<<<(N * 128 / 4 + 255) / 256, 256, 0, stream>>>((float4*)P, (const float4*)Q, N * 128 / 4);
    scatter_kernel<5><<<(E * 32 + 255) / 256, 256, 0, stream>>>(P, Q, ei, E);
    gemm_kernel<128, true><<<(N + 15) / 16, 256, 0, stream>>>(P, g3w1, g3b1, Q, N);
    gemm_kernel<128, false><<<(N + 15) / 16, 256, 0, stream>>>(Q, g3w2, g3b2, P, N);
    // final node features now in P

    // ---- pool + head ----
    init_pool_kernel<<<(NGRAPHS * 128 + 255) / 256, 256, 0, stream>>>(pooled);
    pool_kernel<<<(N + 511) / 512, 128, 0, stream>>>(pooled, P, batch, N);
    head_kernel<<<NGRAPHS, 64, 0, stream>>>(out, pooled, f1w, f1b, f2w, f2b);
}

// Round 2
// 1320.852 us; speedup vs baseline: 5.7251x; 5.7251x over previous
//
#include <hip/hip_runtime.h>
#include <hip/hip_bf16.h>
#include <cmath>

#define NNODES 100000
#define NGRAPHS 64

__device__ __forceinline__ void atomicMaxF(float* addr, float v) {
    if (v >= 0.f) atomicMax((int*)addr, __float_as_int(v));
    else          atomicMin((unsigned int*)addr, __float_as_uint(v));
}

// ---------------- CSR build ----------------

__global__ void hist_kernel(int* __restrict__ cnt, const int* __restrict__ ei, int E) {
    int e = blockIdx.x * blockDim.x + threadIdx.x;
    if (e < E) atomicAdd(&cnt[ei[E + e]], 1);
}

// pass 1: per-block (1024 elems) sums
__global__ __launch_bounds__(256) void scan_partial(const int* __restrict__ cnt,
                                                    int* __restrict__ blocksum, int n) {
    __shared__ int red[256];
    int base = blockIdx.x * 1024;
    int t = threadIdx.x;
    int s = 0;
#pragma unroll
    for (int i = 0; i < 4; ++i) {
        int idx = base + t * 4 + i;
        if (idx < n) s += cnt[idx];
    }
    red[t] = s;
    __syncthreads();
    for (int off = 128; off > 0; off >>= 1) {
        if (t < off) red[t] += red[t + off];
        __syncthreads();
    }
    if (t == 0) blocksum[blockIdx.x] = red[0];
}

// pass 2: exclusive scan of block sums (nblk ~ 98), also writes start[N]=E
__global__ void scan_top(int* __restrict__ blocksum, int nblk, int* __restrict__ startN) {
    if (threadIdx.x == 0 && blockIdx.x == 0) {
        int acc = 0;
        for (int i = 0; i < nblk; ++i) { int v = blocksum[i]; blocksum[i] = acc; acc += v; }
        *startN = acc;
    }
}

// pass 3: in-place exclusive scan (start aliased with cnt), also init cursor
__global__ __launch_bounds__(256) void scan_final(int* __restrict__ start,
                                                  const int* __restrict__ blocksum,
                                                  int* __restrict__ cursor, int n) {
    __shared__ int tsum[256];
    int base = blockIdx.x * 1024;
    int t = threadIdx.x;
    int v[4]; int s = 0;
#pragma unroll
    for (int i = 0; i < 4; ++i) {
        int idx = base + t * 4 + i;
        v[i] = (idx < n) ? start[idx] : 0;
        s += v[i];
    }
    int x = s;
    tsum[t] = x;
    __syncthreads();
    for (int off = 1; off < 256; off <<= 1) {
        int y = (t >= off) ? tsum[t - off] : 0;
        __syncthreads();
        x += y;
        tsum[t] = x;
        __syncthreads();
    }
    int run = x - s + blocksum[blockIdx.x];
#pragma unroll
    for (int i = 0; i < 4; ++i) {
        int idx = base + t * 4 + i;
        if (idx < n) { start[idx] = run; cursor[idx] = run; }
        run += v[i];
    }
}

__global__ void fill_kernel(int* __restrict__ csr, int* __restrict__ cursor,
                            const int* __restrict__ ei, int E) {
    int e = blockIdx.x * blockDim.x + threadIdx.x;
    if (e < E) {
        int slot = atomicAdd(&cursor[ei[E + e]], 1);
        csr[slot] = ei[e];
    }
}

// ---------------- aggregation: out[i] = h[i] + sum_{j in N(i)} h[j] ----------------
// LANES lanes per node, each lane owns one float4 (D = LANES*4)
template<int LANES>
__global__ __launch_bounds__(256) void gather_kernel(float* __restrict__ outbuf,
                                                     const float* __restrict__ h,
                                                     const int* __restrict__ start,
                                                     const int* __restrict__ csr, int N) {
    const int D = LANES * 4;
    int t = threadIdx.x;
    int node = blockIdx.x * (256 / LANES) + t / LANES;
    int lane = t % LANES;
    if (node >= N) return;
    float4 acc = *(const float4*)(h + (size_t)node * D + lane * 4);
    int p0 = start[node], p1 = start[node + 1];
    for (int p = p0; p < p1; ++p) {
        int j = csr[p];
        const float4 v = *(const float4*)(h + (size_t)j * D + lane * 4);
        acc.x += v.x; acc.y += v.y; acc.z += v.z; acc.w += v.w;
    }
    *(float4*)(outbuf + (size_t)node * D + lane * 4) = acc;
}

// ---------------- GEMM: out[M x 128] = A[M x K] @ W[K x 128] + bias ----------------
template<int K, bool RELU>
__global__ __launch_bounds__(256) void gemm_kernel(const float* __restrict__ A,
                                                   const float* __restrict__ W,
                                                   const float* __restrict__ bias,
                                                   float* __restrict__ out, int M) {
    __shared__ float wlds[64 * 128];
    __shared__ float alds[16 * K];
    const int tid = threadIdx.x;
    const int r0 = blockIdx.x * 16;

    {
        int nv = 16 * K;
        int rem = (M - r0) * K;
        if (rem < nv) nv = rem;
        const float4* Asrc = (const float4*)(A + (size_t)r0 * K);
        float4* Adst = (float4*)alds;
        for (int i = tid; i < nv / 4; i += 256) Adst[i] = Asrc[i];
    }

    const int row = tid >> 4;
    const int c0 = (tid & 15) * 8;
    float acc[8];
#pragma unroll
    for (int j = 0; j < 8; ++j) acc[j] = 0.f;

    for (int kp = 0; kp < K; kp += 64) {
        __syncthreads();
        const float4* Wsrc = (const float4*)(W + (size_t)kp * 128);
        for (int i = tid; i < (64 * 128) / 4; i += 256) ((float4*)wlds)[i] = Wsrc[i];
        __syncthreads();
#pragma unroll 8
        for (int k = 0; k < 64; ++k) {
            float a = alds[row * K + kp + k];
            const float* wrow = &wlds[k * 128 + c0];
#pragma unroll
            for (int j = 0; j < 8; ++j) acc[j] = fmaf(a, wrow[j], acc[j]);
        }
    }

    if (r0 + row < M) {
        float* orow = out + (size_t)(r0 + row) * 128 + c0;
        float t[8];
#pragma unroll
        for (int j = 0; j < 8; ++j) {
            float v = acc[j] + bias[c0 + j];
            if (RELU) v = fmaxf(v, 0.f);
            t[j] = v;
        }
        *(float4*)(orow) = make_float4(t[0], t[1], t[2], t[3]);
        *(float4*)(orow + 4) = make_float4(t[4], t[5], t[6], t[7]);
    }
}

// ---------------- pool + head ----------------

__global__ void init_pool_kernel(float* p) {
    int i = blockIdx.x * blockDim.x + threadIdx.x;
    if (i < NGRAPHS * 128) p[i] = -INFINITY;
}

__global__ __launch_bounds__(128) void pool_kernel(float* __restrict__ pooled,
                                                   const float* __restrict__ h,
                                                   const int* __restrict__ batch, int N) {
    const int f = threadIdx.x;
    int n0 = blockIdx.x * 512;
    int n1 = n0 + 512;
    if (n1 > N) n1 = N;
    int cur = -1;
    float run = -INFINITY;
    for (int n = n0; n < n1; ++n) {
        int g = batch[n];
        if (g != cur) {
            if (cur >= 0) atomicMaxF(&pooled[cur * 128 + f], run);
            cur = g;
            run = -INFINITY;
        }
        run = fmaxf(run, h[(size_t)n * 128 + f]);
    }
    if (cur >= 0) atomicMaxF(&pooled[cur * 128 + f], run);
}

__global__ __launch_bounds__(64) void head_kernel(float* __restrict__ out,
                                                  const float* __restrict__ pooled,
                                                  const float* __restrict__ w1,
                                                  const float* __restrict__ b1,
                                                  const float* __restrict__ w2,
                                                  const float* __restrict__ b2) {
    int g = blockIdx.x, t = threadIdx.x;
    __shared__ float a[64];
    __shared__ float o[10];
    __shared__ float red[2];
    const float* pg = pooled + g * 128;
    float acc = b1[t];
    for (int k = 0; k < 128; ++k) acc = fmaf(pg[k], w1[k * 64 + t], acc);
    a[t] = fmaxf(acc, 0.f);
    __syncthreads();
    if (t < 10) {
        float s = b2[t];
        for (int k = 0; k < 64; ++k) s = fmaf(a[k], w2[k * 10 + t], s);
        o[t] = s;
    }
    __syncthreads();
    if (t == 0) {
        float m = -INFINITY;
        for (int c = 0; c < 10; ++c) m = fmaxf(m, o[c]);
        float se = 0.f;
        for (int c = 0; c < 10; ++c) se += expf(o[c] - m);
        red[0] = m;
        red[1] = logf(se);
    }
    __syncthreads();
    if (t < 10) out[g * 10 + t] = o[t] - red[0] - red[1];
}

extern "C" void kernel_launch(void* const* d_in, const int* in_sizes, int n_in,
                              void* d_out, int out_size, void* d_ws, size_t ws_size,
                              hipStream_t stream) {
    const float* x    = (const float*)d_in[0];
    const int* ei     = (const int*)d_in[1];
    const int* batch  = (const int*)d_in[2];
    const float* g1w1 = (const float*)d_in[3];  const float* g1b1 = (const float*)d_in[4];
    const float* g1w2 = (const float*)d_in[5];  const float* g1b2 = (const float*)d_in[6];
    const float* g2w1 = (const float*)d_in[7];  const float* g2b1 = (const float*)d_in[8];
    const float* g2w2 = (const float*)d_in[9];  const float* g2b2 = (const float*)d_in[10];
    const float* g3w1 = (const float*)d_in[11]; const float* g3b1 = (const float*)d_in[12];
    const float* g3w2 = (const float*)d_in[13]; const float* g3b2 = (const float*)d_in[14];
    const float* f1w  = (const float*)d_in[15]; const float* f1b  = (const float*)d_in[16];
    const float* f2w  = (const float*)d_in[17]; const float* f2b  = (const float*)d_in[18];
    float* out = (float*)d_out;

    const int N = NNODES;
    const int E = in_sizes[1] / 2;
    const int nblk = (N + 1023) / 1024;

    float* P = (float*)d_ws;                    // N*128
    float* Q = P + (size_t)N * 128;             // N*128
    float* pooled = Q + (size_t)N * 128;        // 64*128
    int* start = (int*)(pooled + NGRAPHS * 128);// N+1 (doubles as cnt)
    int* cursor = start + (N + 1);              // N
    int* blocksum = cursor + N;                 // nblk (<=128)
    int* csr = blocksum + 128;                  // E

    // ---- CSR build ----
    hipMemsetAsync(start, 0, (size_t)N * sizeof(int), stream);
    hist_kernel<<<(E + 255) / 256, 256, 0, stream>>>(start, ei, E);
    scan_partial<<<nblk, 256, 0, stream>>>(start, blocksum, N);
    scan_top<<<1, 64, 0, stream>>>(blocksum, nblk, start + N);
    scan_final<<<nblk, 256, 0, stream>>>(start, blocksum, cursor, N);
    fill_kernel<<<(E + 255) / 256, 256, 0, stream>>>(csr, cursor, ei, E);

    // ---- layer 1 (D_in = 64) ----
    gather_kernel<16><<<(N + 15) / 16, 256, 0, stream>>>(P, x, start, csr, N);
    gemm_kernel<64, true><<<(N + 15) / 16, 256, 0, stream>>>(P, g1w1, g1b1, Q, N);
    gemm_kernel<128, false><<<(N + 15) / 16, 256, 0, stream>>>(Q, g1w2, g1b2, P, N);

    // ---- layer 2 ----
    gather_kernel<32><<<(N + 7) / 8, 256, 0, stream>>>(Q, P, start, csr, N);
    gemm_kernel<128, true><<<(N + 15) / 16, 256, 0, stream>>>(Q, g2w1, g2b1, P, N);
    gemm_kernel<128, false><<<(N + 15) / 16, 256, 0, stream>>>(P, g2w2, g2b2, Q, N);

    // ---- layer 3 ----
    gather_kernel<32><<<(N + 7) / 8, 256, 0, stream>>>(P, Q, start, csr, N);
    gemm_kernel<128, true><<<(N + 15) / 16, 256, 0, stream>>>(P, g3w1, g3b1, Q, N);
    gemm_kernel<128, false><<<(N + 15) / 16, 256, 0, stream>>>(Q, g3w2, g3b2, P, N);
    // final node features in P

    // ---- pool + head ----
    init_pool_kernel<<<(NGRAPHS * 128 + 255) / 256, 256, 0, stream>>>(pooled);
    pool_kernel<<<(N + 511) / 512, 128, 0, stream>>>(pooled, P, batch, N);
    head_kernel<<<NGRAPHS, 64, 0, stream>>>(out, pooled, f1w, f1b, f2w, f2b);
}

// Round 3
// 607.177 us; speedup vs baseline: 12.4544x; 2.1754x over previous
//
#include <hip/hip_runtime.h>
#include <hip/hip_bf16.h>
#include <cmath>

#define NNODES 100000
#define NGRAPHS 64

typedef __attribute__((ext_vector_type(8))) short bf16x8;
typedef __attribute__((ext_vector_type(4))) float f32x4;

__device__ __forceinline__ float bf2f(unsigned short u) {
    unsigned int v = ((unsigned int)u) << 16;
    return __uint_as_float(v);
}
__device__ __forceinline__ unsigned short f2bf(float f) {
    unsigned int v = __float_as_uint(f);
    unsigned int r = (v + 0x7fffu + ((v >> 16) & 1u)) >> 16;
    return (unsigned short)r;
}

__device__ __forceinline__ void atomicMaxF(float* addr, float v) {
    if (v >= 0.f) atomicMax((int*)addr, __float_as_int(v));
    else          atomicMin((unsigned int*)addr, __float_as_uint(v));
}

// ---------------- x (f32) -> bf16 ----------------
__global__ void convert_kernel(unsigned short* __restrict__ dst, const float* __restrict__ src, int n4) {
    int i = blockIdx.x * blockDim.x + threadIdx.x;
    if (i >= n4) return;
    float4 v = ((const float4*)src)[i];
    unsigned short o[4] = { f2bf(v.x), f2bf(v.y), f2bf(v.z), f2bf(v.w) };
    ((uint2*)dst)[i] = *(uint2*)o;
}

// ---------------- CSR build ----------------
__global__ void hist_kernel(int* __restrict__ cnt, const int* __restrict__ ei, int E) {
    int e = blockIdx.x * blockDim.x + threadIdx.x;
    if (e < E) atomicAdd(&cnt[ei[E + e]], 1);
}

__global__ __launch_bounds__(256) void scan_partial(const int* __restrict__ cnt,
                                                    int* __restrict__ blocksum, int n) {
    __shared__ int red[256];
    int base = blockIdx.x * 1024;
    int t = threadIdx.x;
    int s = 0;
#pragma unroll
    for (int i = 0; i < 4; ++i) {
        int idx = base + t * 4 + i;
        if (idx < n) s += cnt[idx];
    }
    red[t] = s;
    __syncthreads();
    for (int off = 128; off > 0; off >>= 1) {
        if (t < off) red[t] += red[t + off];
        __syncthreads();
    }
    if (t == 0) blocksum[blockIdx.x] = red[0];
}

__global__ void scan_top(int* __restrict__ blocksum, int nblk, int* __restrict__ startN) {
    if (threadIdx.x == 0 && blockIdx.x == 0) {
        int acc = 0;
        for (int i = 0; i < nblk; ++i) { int v = blocksum[i]; blocksum[i] = acc; acc += v; }
        *startN = acc;
    }
}

__global__ __launch_bounds__(256) void scan_final(int* __restrict__ start,
                                                  const int* __restrict__ blocksum,
                                                  int* __restrict__ cursor, int n) {
    __shared__ int tsum[256];
    int base = blockIdx.x * 1024;
    int t = threadIdx.x;
    int v[4]; int s = 0;
#pragma unroll
    for (int i = 0; i < 4; ++i) {
        int idx = base + t * 4 + i;
        v[i] = (idx < n) ? start[idx] : 0;
        s += v[i];
    }
    int x = s;
    tsum[t] = x;
    __syncthreads();
    for (int off = 1; off < 256; off <<= 1) {
        int y = (t >= off) ? tsum[t - off] : 0;
        __syncthreads();
        x += y;
        tsum[t] = x;
        __syncthreads();
    }
    int run = x - s + blocksum[blockIdx.x];
#pragma unroll
    for (int i = 0; i < 4; ++i) {
        int idx = base + t * 4 + i;
        if (idx < n) { start[idx] = run; cursor[idx] = run; }
        run += v[i];
    }
}

__global__ void fill_kernel(int* __restrict__ csr, int* __restrict__ cursor,
                            const int* __restrict__ ei, int E) {
    int e = blockIdx.x * blockDim.x + threadIdx.x;
    if (e < E) {
        int slot = atomicAdd(&cursor[ei[E + e]], 1);
        csr[slot] = ei[e];
    }
}

// ---------------- aggregation (bf16 in, bf16 out): out[i] = h[i] + sum_j h[j] ----------------
// LANES threads per node; each lane owns 8 bf16 (16B). D = LANES*8.
template<int LANES>
__global__ __launch_bounds__(256) void gather_kernel(unsigned short* __restrict__ outb,
                                                     const unsigned short* __restrict__ h,
                                                     const int* __restrict__ start,
                                                     const int* __restrict__ csr, int N) {
    const int D = LANES * 8;
    int t = threadIdx.x;
    int node = blockIdx.x * (256 / LANES) + t / LANES;
    if (node >= N) return;
    int lane = t % LANES;
    float acc[8];
    {
        uint4 v = *(const uint4*)(h + (size_t)node * D + lane * 8);
        const unsigned short* q = (const unsigned short*)&v;
#pragma unroll
        for (int i = 0; i < 8; ++i) acc[i] = bf2f(q[i]);
    }
    int p0 = start[node], p1 = start[node + 1];
    for (int p = p0; p < p1; ++p) {
        int j = csr[p];
        uint4 v = *(const uint4*)(h + (size_t)j * D + lane * 8);
        const unsigned short* q = (const unsigned short*)&v;
#pragma unroll
        for (int i = 0; i < 8; ++i) acc[i] += bf2f(q[i]);
    }
    unsigned short o[8];
#pragma unroll
    for (int i = 0; i < 8; ++i) o[i] = f2bf(acc[i]);
    *(uint4*)(outb + (size_t)node * D + lane * 8) = *(uint4*)o;
}

// ---------------- W (K x 128 f32) -> MFMA B-fragment pack (bf16) ----------------
// Wp[((kp*8 + n0)*64 + l)*8 + j] = bf16( W[(kp*32 + (l>>4)*8 + j)*128 + n0*16 + (l&15)] )
__global__ void pack_w_kernel(unsigned short* __restrict__ wp, const float* __restrict__ W, int K) {
    int t = blockIdx.x * blockDim.x + threadIdx.x;
    int total = (K / 32) * 8 * 64;
    if (t >= total) return;
    int l = t & 63;
    int n0 = (t >> 6) & 7;
    int kp = t >> 9;
    unsigned short o[8];
#pragma unroll
    for (int j = 0; j < 8; ++j)
        o[j] = f2bf(W[(size_t)(kp * 32 + (l >> 4) * 8 + j) * 128 + n0 * 16 + (l & 15)]);
    *(uint4*)(wp + (size_t)t * 8) = *(uint4*)o;
}

// ---------------- MFMA GEMM: out[M x 128](bf16) = A[M x K](bf16) @ W + bias ----------------
// 256 thr = 4 waves; wave computes 16 rows x 128 cols. No LDS.
template<int K, bool RELU>
__global__ __launch_bounds__(256) void mfma_gemm(const unsigned short* __restrict__ A,
                                                 const unsigned short* __restrict__ Wp,
                                                 const float* __restrict__ bias,
                                                 unsigned short* __restrict__ out, int M) {
    const int l = threadIdx.x & 63;
    const int w = threadIdx.x >> 6;
    const int mbase = (blockIdx.x * 4 + w) * 16;
    const int kgrp = l >> 4;
    int row_a = mbase + (l & 15);
    if (row_a >= M) row_a = M - 1;

    f32x4 acc[8];
#pragma unroll
    for (int i = 0; i < 8; ++i) acc[i] = (f32x4){0.f, 0.f, 0.f, 0.f};

#pragma unroll
    for (int kp = 0; kp < K / 32; ++kp) {
        bf16x8 a = *(const bf16x8*)(A + (size_t)row_a * K + kp * 32 + kgrp * 8);
#pragma unroll
        for (int n0 = 0; n0 < 8; ++n0) {
            bf16x8 b = *(const bf16x8*)(Wp + ((size_t)(kp * 8 + n0) * 64 + l) * 8);
            acc[n0] = __builtin_amdgcn_mfma_f32_16x16x32_bf16(a, b, acc[n0], 0, 0, 0);
        }
    }

    const int col = l & 15;
#pragma unroll
    for (int n0 = 0; n0 < 8; ++n0) {
        float bv = bias[n0 * 16 + col];
#pragma unroll
        for (int r = 0; r < 4; ++r) {
            int row = mbase + kgrp * 4 + r;
            if (row < M) {
                float v = acc[n0][r] + bv;
                if (RELU) v = fmaxf(v, 0.f);
                out[(size_t)row * 128 + n0 * 16 + col] = f2bf(v);
            }
        }
    }
}

// ---------------- pool + head ----------------
__global__ void init_pool_kernel(float* p) {
    int i = blockIdx.x * blockDim.x + threadIdx.x;
    if (i < NGRAPHS * 128) p[i] = -INFINITY;
}

// 128 threads (one per feature), each block scans 128 consecutive nodes
__global__ __launch_bounds__(128) void pool_kernel(float* __restrict__ pooled,
                                                   const unsigned short* __restrict__ h,
                                                   const int* __restrict__ batch, int N) {
    const int f = threadIdx.x;
    int n0 = blockIdx.x * 128;
    int n1 = n0 + 128;
    if (n1 > N) n1 = N;
    int cur = -1;
    float run = -INFINITY;
    for (int n = n0; n < n1; ++n) {
        int g = batch[n];
        if (g != cur) {
            if (cur >= 0) atomicMaxF(&pooled[cur * 128 + f], run);
            cur = g;
            run = -INFINITY;
        }
        run = fmaxf(run, bf2f(h[(size_t)n * 128 + f]));
    }
    if (cur >= 0) atomicMaxF(&pooled[cur * 128 + f], run);
}

__global__ __launch_bounds__(64) void head_kernel(float* __restrict__ out,
                                                  const float* __restrict__ pooled,
                                                  const float* __restrict__ w1,
                                                  const float* __restrict__ b1,
                                                  const float* __restrict__ w2,
                                                  const float* __restrict__ b2) {
    int g = blockIdx.x, t = threadIdx.x;
    __shared__ float a[64];
    __shared__ float o[10];
    __shared__ float red[2];
    const float* pg = pooled + g * 128;
    float acc = b1[t];
    for (int k = 0; k < 128; ++k) acc = fmaf(pg[k], w1[k * 64 + t], acc);
    a[t] = fmaxf(acc, 0.f);
    __syncthreads();
    if (t < 10) {
        float s = b2[t];
        for (int k = 0; k < 64; ++k) s = fmaf(a[k], w2[k * 10 + t], s);
        o[t] = s;
    }
    __syncthreads();
    if (t == 0) {
        float m = -INFINITY;
        for (int c = 0; c < 10; ++c) m = fmaxf(m, o[c]);
        float se = 0.f;
        for (int c = 0; c < 10; ++c) se += expf(o[c] - m);
        red[0] = m;
        red[1] = logf(se);
    }
    __syncthreads();
    if (t < 10) out[g * 10 + t] = o[t] - red[0] - red[1];
}

extern "C" void kernel_launch(void* const* d_in, const int* in_sizes, int n_in,
                              void* d_out, int out_size, void* d_ws, size_t ws_size,
                              hipStream_t stream) {
    const float* x    = (const float*)d_in[0];
    const int* ei     = (const int*)d_in[1];
    const int* batch  = (const int*)d_in[2];
    const float* g1w1 = (const float*)d_in[3];  const float* g1b1 = (const float*)d_in[4];
    const float* g1w2 = (const float*)d_in[5];  const float* g1b2 = (const float*)d_in[6];
    const float* g2w1 = (const float*)d_in[7];  const float* g2b1 = (const float*)d_in[8];
    const float* g2w2 = (const float*)d_in[9];  const float* g2b2 = (const float*)d_in[10];
    const float* g3w1 = (const float*)d_in[11]; const float* g3b1 = (const float*)d_in[12];
    const float* g3w2 = (const float*)d_in[13]; const float* g3b2 = (const float*)d_in[14];
    const float* f1w  = (const float*)d_in[15]; const float* f1b  = (const float*)d_in[16];
    const float* f2w  = (const float*)d_in[17]; const float* f2b  = (const float*)d_in[18];
    float* out = (float*)d_out;

    const int N = NNODES;
    const int E = in_sizes[1] / 2;
    const int nblk = (N + 1023) / 1024;

    char* base = (char*)d_ws;
    auto alloc = [&](size_t bytes) { char* p = base; base += (bytes + 255) & ~(size_t)255; return p; };

    unsigned short* B1 = (unsigned short*)alloc((size_t)N * 128 * 2);
    unsigned short* B2 = (unsigned short*)alloc((size_t)N * 128 * 2);
    unsigned short* B0 = (unsigned short*)alloc((size_t)N * 64 * 2);   // x bf16
    unsigned short* B3 = (unsigned short*)alloc((size_t)N * 64 * 2);   // gather1 out
    int* csr      = (int*)alloc((size_t)E * 4);
    int* start    = (int*)alloc((size_t)(N + 1) * 4);
    int* cursor   = (int*)alloc((size_t)N * 4);
    int* blocksum = (int*)alloc(512);
    float* pooled = (float*)alloc((size_t)NGRAPHS * 128 * 4);
    unsigned short* wp1 = (unsigned short*)alloc((size_t)64 * 128 * 2);
    unsigned short* wp2 = (unsigned short*)alloc((size_t)128 * 128 * 2);
    unsigned short* wp3 = (unsigned short*)alloc((size_t)128 * 128 * 2);
    unsigned short* wp4 = (unsigned short*)alloc((size_t)128 * 128 * 2);
    unsigned short* wp5 = (unsigned short*)alloc((size_t)128 * 128 * 2);
    unsigned short* wp6 = (unsigned short*)alloc((size_t)128 * 128 * 2);

    // ---- CSR build ----
    hipMemsetAsync(start, 0, (size_t)N * sizeof(int), stream);
    hist_kernel<<<(E + 255) / 256, 256, 0, stream>>>(start, ei, E);
    scan_partial<<<nblk, 256, 0, stream>>>(start, blocksum, N);
    scan_top<<<1, 64, 0, stream>>>(blocksum, nblk, start + N);
    scan_final<<<nblk, 256, 0, stream>>>(start, blocksum, cursor, N);
    fill_kernel<<<(E + 255) / 256, 256, 0, stream>>>(csr, cursor, ei, E);

    // ---- conversions / packs ----
    convert_kernel<<<(N * 64 / 4 + 255) / 256, 256, 0, stream>>>(B0, x, N * 64 / 4);
    pack_w_kernel<<<4, 256, 0, stream>>>(wp1, g1w1, 64);
    pack_w_kernel<<<8, 256, 0, stream>>>(wp2, g1w2, 128);
    pack_w_kernel<<<8, 256, 0, stream>>>(wp3, g2w1, 128);
    pack_w_kernel<<<8, 256, 0, stream>>>(wp4, g2w2, 128);
    pack_w_kernel<<<8, 256, 0, stream>>>(wp5, g3w1, 128);
    pack_w_kernel<<<8, 256, 0, stream>>>(wp6, g3w2, 128);
    init_pool_kernel<<<(NGRAPHS * 128 + 255) / 256, 256, 0, stream>>>(pooled);

    const int ggrid = (N + 63) / 64;

    // ---- layer 1 (K=64) ----
    gather_kernel<8><<<(N + 31) / 32, 256, 0, stream>>>(B3, B0, start, csr, N);
    mfma_gemm<64, true><<<ggrid, 256, 0, stream>>>(B3, wp1, g1b1, B1, N);
    mfma_gemm<128, false><<<ggrid, 256, 0, stream>>>(B1, wp2, g1b2, B2, N);   // h1 in B2

    // ---- layer 2 ----
    gather_kernel<16><<<(N + 15) / 16, 256, 0, stream>>>(B1, B2, start, csr, N);
    mfma_gemm<128, true><<<ggrid, 256, 0, stream>>>(B1, wp3, g2b1, B2, N);
    mfma_gemm<128, false><<<ggrid, 256, 0, stream>>>(B2, wp4, g2b2, B1, N);   // h2 in B1

    // ---- layer 3 ----
    gather_kernel<16><<<(N + 15) / 16, 256, 0, stream>>>(B2, B1, start, csr, N);
    mfma_gemm<128, true><<<ggrid, 256, 0, stream>>>(B2, wp5, g3b1, B1, N);
    mfma_gemm<128, false><<<ggrid, 256, 0, stream>>>(B1, wp6, g3b2, B2, N);   // h3 in B2

    // ---- pool + head ----
    pool_kernel<<<(N + 127) / 128, 128, 0, stream>>>(pooled, B2, batch, N);
    head_kernel<<<NGRAPHS, 64, 0, stream>>>(out, pooled, f1w, f1b, f2w, f2b);
}

// Round 4
// 491.349 us; speedup vs baseline: 15.3903x; 1.2357x over previous
//
#include <hip/hip_runtime.h>
#include <hip/hip_bf16.h>
#include <cmath>

#define NNODES 100000
#define NGRAPHS 64
#define SHIFT 10
#define NPB 1024                 // nodes per bucket
#define NB 98                    // ceil(NNODES / NPB)
#define BIN_CHUNK 4096

typedef __attribute__((ext_vector_type(8))) short bf16x8;
typedef __attribute__((ext_vector_type(4))) float f32x4;

__device__ __forceinline__ float bf2f(unsigned short u) {
    unsigned int v = ((unsigned int)u) << 16;
    return __uint_as_float(v);
}
__device__ __forceinline__ unsigned short f2bf(float f) {
    unsigned int v = __float_as_uint(f);
    unsigned int r = (v + 0x7fffu + ((v >> 16) & 1u)) >> 16;
    return (unsigned short)r;
}

__device__ __forceinline__ void atomicMaxF(float* addr, float v) {
    if (v >= 0.f) atomicMax((int*)addr, __float_as_int(v));
    else          atomicMin((unsigned int*)addr, __float_as_uint(v));
}

// ---------------- x (f32) -> bf16 ----------------
__global__ void convert_kernel(unsigned short* __restrict__ dst, const float* __restrict__ src, int n4) {
    int i = blockIdx.x * blockDim.x + threadIdx.x;
    if (i >= n4) return;
    float4 v = ((const float4*)src)[i];
    unsigned short o[4] = { f2bf(v.x), f2bf(v.y), f2bf(v.z), f2bf(v.w) };
    ((uint2*)dst)[i] = *(uint2*)o;
}

// ---------------- CSR build ----------------
__global__ void hist_kernel(int* __restrict__ cnt, const int* __restrict__ ei, int E) {
    int e = blockIdx.x * blockDim.x + threadIdx.x;
    if (e < E) atomicAdd(&cnt[ei[E + e]], 1);
}

__global__ __launch_bounds__(256) void scan_partial(const int* __restrict__ cnt,
                                                    int* __restrict__ blocksum, int n) {
    __shared__ int red[256];
    int base = blockIdx.x * 1024;
    int t = threadIdx.x;
    int s = 0;
#pragma unroll
    for (int i = 0; i < 4; ++i) {
        int idx = base + t * 4 + i;
        if (idx < n) s += cnt[idx];
    }
    red[t] = s;
    __syncthreads();
    for (int off = 128; off > 0; off >>= 1) {
        if (t < off) red[t] += red[t + off];
        __syncthreads();
    }
    if (t == 0) blocksum[blockIdx.x] = red[0];
}

__global__ void scan_top(int* __restrict__ blocksum, int nblk, int* __restrict__ startN) {
    if (threadIdx.x == 0 && blockIdx.x == 0) {
        int acc = 0;
        for (int i = 0; i < nblk; ++i) { int v = blocksum[i]; blocksum[i] = acc; acc += v; }
        *startN = acc;
    }
}

__global__ __launch_bounds__(256) void scan_final(int* __restrict__ start,
                                                  const int* __restrict__ blocksum, int n) {
    __shared__ int tsum[256];
    int base = blockIdx.x * 1024;
    int t = threadIdx.x;
    int v[4]; int s = 0;
#pragma unroll
    for (int i = 0; i < 4; ++i) {
        int idx = base + t * 4 + i;
        v[i] = (idx < n) ? start[idx] : 0;
        s += v[i];
    }
    int x = s;
    tsum[t] = x;
    __syncthreads();
    for (int off = 1; off < 256; off <<= 1) {
        int y = (t >= off) ? tsum[t - off] : 0;
        __syncthreads();
        x += y;
        tsum[t] = x;
        __syncthreads();
    }
    int run = x - s + blocksum[blockIdx.x];
#pragma unroll
    for (int i = 0; i < 4; ++i) {
        int idx = base + t * 4 + i;
        if (idx < n) start[idx] = run;
        run += v[i];
    }
}

__global__ void init_gcur(int* __restrict__ gcur, const int* __restrict__ start) {
    int b = threadIdx.x;
    if (b < NB) {
        int n = b << SHIFT;
        if (n > NNODES) n = NNODES;
        gcur[b] = start[n];
    }
}

// phase 1: block-level counting sort of edges into NB bucket-contiguous regions
__global__ __launch_bounds__(256) void bin_kernel(unsigned int* __restrict__ binned,
                                                  int* __restrict__ gcur,
                                                  const int* __restrict__ ei, int E) {
    __shared__ int cnt[NB];
    __shared__ int gbase[NB];
    __shared__ int loff[NB];
    int t = threadIdx.x;
    int base = blockIdx.x * BIN_CHUNK;
    for (int i = t; i < NB; i += 256) { cnt[i] = 0; loff[i] = 0; }
    __syncthreads();
    unsigned int pk[16]; short bk[16]; int ne = 0;
#pragma unroll
    for (int i = 0; i < 16; ++i) {
        int e = base + t + i * 256;
        if (e < E) {
            int s = ei[e], d = ei[E + e];
            int b = d >> SHIFT;
            pk[ne] = ((unsigned int)s << SHIFT) | (unsigned int)(d & (NPB - 1));
            bk[ne] = (short)b;
            ne++;
            atomicAdd(&cnt[b], 1);
        }
    }
    __syncthreads();
    for (int i = t; i < NB; i += 256)
        gbase[i] = cnt[i] ? atomicAdd(&gcur[i], cnt[i]) : 0;
    __syncthreads();
    for (int i = 0; i < ne; ++i) {
        int b = bk[i];
        int pos = atomicAdd(&loff[b], 1);
        binned[gbase[b] + pos] = pk[i];
    }
}

// phase 2: one block per bucket; LDS per-node cursors; csr writes stay in-bucket
__global__ __launch_bounds__(256) void fill2_kernel(int* __restrict__ csr,
                                                    const unsigned int* __restrict__ binned,
                                                    const int* __restrict__ start, int N) {
    __shared__ int cur[NPB];
    int b = blockIdx.x;
    int n0 = b << SHIFT;
    int n1 = n0 + NPB;
    if (n1 > N) n1 = N;
    int t = threadIdx.x;
    for (int i = t; i < n1 - n0; i += 256) cur[i] = start[n0 + i];
    __syncthreads();
    int p0 = start[n0], p1 = start[n1];
    for (int p = p0 + t; p < p1; p += 256) {
        unsigned int v = binned[p];
        int slot = atomicAdd(&cur[v & (NPB - 1)], 1);
        csr[slot] = (int)(v >> SHIFT);
    }
}

// ---------------- aggregation (bf16): out[i] = h[i] + sum_j h[j] ----------------
template<int LANES>
__global__ __launch_bounds__(256) void gather_kernel(unsigned short* __restrict__ outb,
                                                     const unsigned short* __restrict__ h,
                                                     const int* __restrict__ start,
                                                     const int* __restrict__ csr, int N) {
    const int D = LANES * 8;
    int t = threadIdx.x;
    int node = blockIdx.x * (256 / LANES) + t / LANES;
    if (node >= N) return;
    int lane = t % LANES;
    float acc[8];
    {
        uint4 v = *(const uint4*)(h + (size_t)node * D + lane * 8);
        const unsigned short* q = (const unsigned short*)&v;
#pragma unroll
        for (int i = 0; i < 8; ++i) acc[i] = bf2f(q[i]);
    }
    int p0 = start[node], p1 = start[node + 1];
    if (p0 < p1) {
        int j = csr[p0];
        for (int p = p0 + 1; p < p1; ++p) {
            int jn = csr[p];
            uint4 v = *(const uint4*)(h + (size_t)j * D + lane * 8);
            const unsigned short* q = (const unsigned short*)&v;
#pragma unroll
            for (int i = 0; i < 8; ++i) acc[i] += bf2f(q[i]);
            j = jn;
        }
        uint4 v = *(const uint4*)(h + (size_t)j * D + lane * 8);
        const unsigned short* q = (const unsigned short*)&v;
#pragma unroll
        for (int i = 0; i < 8; ++i) acc[i] += bf2f(q[i]);
    }
    unsigned short o[8];
#pragma unroll
    for (int i = 0; i < 8; ++i) o[i] = f2bf(acc[i]);
    *(uint4*)(outb + (size_t)node * D + lane * 8) = *(uint4*)o;
}

// ---------------- W (K x 128 f32) -> MFMA B-fragment pack (bf16) ----------------
__global__ void pack_w_kernel(unsigned short* __restrict__ wp, const float* __restrict__ W, int K) {
    int t = blockIdx.x * blockDim.x + threadIdx.x;
    int total = (K / 32) * 8 * 64;
    if (t >= total) return;
    int l = t & 63;
    int n0 = (t >> 6) & 7;
    int kp = t >> 9;
    unsigned short o[8];
#pragma unroll
    for (int j = 0; j < 8; ++j)
        o[j] = f2bf(W[(size_t)(kp * 32 + (l >> 4) * 8 + j) * 128 + n0 * 16 + (l & 15)]);
    *(uint4*)(wp + (size_t)t * 8) = *(uint4*)o;
}

// ---------------- MFMA GEMM: out[M x 128](bf16) = A[M x K](bf16) @ W + bias ----------------
template<int K, bool RELU>
__global__ __launch_bounds__(256) void mfma_gemm(const unsigned short* __restrict__ A,
                                                 const unsigned short* __restrict__ Wp,
                                                 const float* __restrict__ bias,
                                                 unsigned short* __restrict__ out, int M) {
    const int l = threadIdx.x & 63;
    const int w = threadIdx.x >> 6;
    const int mbase = (blockIdx.x * 4 + w) * 16;
    const int kgrp = l >> 4;
    int row_a = mbase + (l & 15);
    if (row_a >= M) row_a = M - 1;

    f32x4 acc[8];
#pragma unroll
    for (int i = 0; i < 8; ++i) acc[i] = (f32x4){0.f, 0.f, 0.f, 0.f};

#pragma unroll
    for (int kp = 0; kp < K / 32; ++kp) {
        bf16x8 a = *(const bf16x8*)(A + (size_t)row_a * K + kp * 32 + kgrp * 8);
#pragma unroll
        for (int n0 = 0; n0 < 8; ++n0) {
            bf16x8 b = *(const bf16x8*)(Wp + ((size_t)(kp * 8 + n0) * 64 + l) * 8);
            acc[n0] = __builtin_amdgcn_mfma_f32_16x16x32_bf16(a, b, acc[n0], 0, 0, 0);
        }
    }

    const int col = l & 15;
#pragma unroll
    for (int n0 = 0; n0 < 8; ++n0) {
        float bv = bias[n0 * 16 + col];
#pragma unroll
        for (int r = 0; r < 4; ++r) {
            int row = mbase + kgrp * 4 + r;
            if (row < M) {
                float v = acc[n0][r] + bv;
                if (RELU) v = fmaxf(v, 0.f);
                out[(size_t)row * 128 + n0 * 16 + col] = f2bf(v);
            }
        }
    }
}

// ---------------- pool + head ----------------
__global__ void init_pool_kernel(float* p) {
    int i = blockIdx.x * blockDim.x + threadIdx.x;
    if (i < NGRAPHS * 128) p[i] = -INFINITY;
}

__global__ __launch_bounds__(128) void pool_kernel(float* __restrict__ pooled,
                                                   const unsigned short* __restrict__ h,
                                                   const int* __restrict__ batch, int N) {
    const int f = threadIdx.x;
    int n0 = blockIdx.x * 128;
    int n1 = n0 + 128;
    if (n1 > N) n1 = N;
    int cur = -1;
    float run = -INFINITY;
    for (int n = n0; n < n1; ++n) {
        int g = batch[n];
        if (g != cur) {
            if (cur >= 0) atomicMaxF(&pooled[cur * 128 + f], run);
            cur = g;
            run = -INFINITY;
        }
        run = fmaxf(run, bf2f(h[(size_t)n * 128 + f]));
    }
    if (cur >= 0) atomicMaxF(&pooled[cur * 128 + f], run);
}

__global__ __launch_bounds__(64) void head_kernel(float* __restrict__ out,
                                                  const float* __restrict__ pooled,
                                                  const float* __restrict__ w1,
                                                  const float* __restrict__ b1,
                                                  const float* __restrict__ w2,
                                                  const float* __restrict__ b2) {
    int g = blockIdx.x, t = threadIdx.x;
    __shared__ float a[64];
    __shared__ float o[10];
    __shared__ float red[2];
    const float* pg = pooled + g * 128;
    float acc = b1[t];
    for (int k = 0; k < 128; ++k) acc = fmaf(pg[k], w1[k * 64 + t], acc);
    a[t] = fmaxf(acc, 0.f);
    __syncthreads();
    if (t < 10) {
        float s = b2[t];
        for (int k = 0; k < 64; ++k) s = fmaf(a[k], w2[k * 10 + t], s);
        o[t] = s;
    }
    __syncthreads();
    if (t == 0) {
        float m = -INFINITY;
        for (int c = 0; c < 10; ++c) m = fmaxf(m, o[c]);
        float se = 0.f;
        for (int c = 0; c < 10; ++c) se += expf(o[c] - m);
        red[0] = m;
        red[1] = logf(se);
    }
    __syncthreads();
    if (t < 10) out[g * 10 + t] = o[t] - red[0] - red[1];
}

extern "C" void kernel_launch(void* const* d_in, const int* in_sizes, int n_in,
                              void* d_out, int out_size, void* d_ws, size_t ws_size,
                              hipStream_t stream) {
    const float* x    = (const float*)d_in[0];
    const int* ei     = (const int*)d_in[1];
    const int* batch  = (const int*)d_in[2];
    const float* g1w1 = (const float*)d_in[3];  const float* g1b1 = (const float*)d_in[4];
    const float* g1w2 = (const float*)d_in[5];  const float* g1b2 = (const float*)d_in[6];
    const float* g2w1 = (const float*)d_in[7];  const float* g2b1 = (const float*)d_in[8];
    const float* g2w2 = (const float*)d_in[9];  const float* g2b2 = (const float*)d_in[10];
    const float* g3w1 = (const float*)d_in[11]; const float* g3b1 = (const float*)d_in[12];
    const float* g3w2 = (const float*)d_in[13]; const float* g3b2 = (const float*)d_in[14];
    const float* f1w  = (const float*)d_in[15]; const float* f1b  = (const float*)d_in[16];
    const float* f2w  = (const float*)d_in[17]; const float* f2b  = (const float*)d_in[18];
    float* out = (float*)d_out;

    const int N = NNODES;
    const int E = in_sizes[1] / 2;
    const int nblk = (N + 1023) / 1024;

    char* base = (char*)d_ws;
    auto alloc = [&](size_t bytes) { char* p = base; base += (bytes + 255) & ~(size_t)255; return p; };

    unsigned short* B1 = (unsigned short*)alloc((size_t)N * 128 * 2);
    unsigned short* B2 = (unsigned short*)alloc((size_t)N * 128 * 2);
    unsigned short* B0 = (unsigned short*)alloc((size_t)N * 64 * 2);   // x bf16
    unsigned short* B3 = (unsigned short*)alloc((size_t)N * 64 * 2);   // gather1 out
    int* csr      = (int*)alloc((size_t)E * 4);
    unsigned int* binned = (unsigned int*)alloc((size_t)E * 4);
    int* start    = (int*)alloc((size_t)(N + 1) * 4);
    int* gcur     = (int*)alloc((size_t)(NB + 4) * 4);
    int* blocksum = (int*)alloc(512);
    float* pooled = (float*)alloc((size_t)NGRAPHS * 128 * 4);
    unsigned short* wp1 = (unsigned short*)alloc((size_t)64 * 128 * 2);
    unsigned short* wp2 = (unsigned short*)alloc((size_t)128 * 128 * 2);
    unsigned short* wp3 = (unsigned short*)alloc((size_t)128 * 128 * 2);
    unsigned short* wp4 = (unsigned short*)alloc((size_t)128 * 128 * 2);
    unsigned short* wp5 = (unsigned short*)alloc((size_t)128 * 128 * 2);
    unsigned short* wp6 = (unsigned short*)alloc((size_t)128 * 128 * 2);

    // ---- CSR build ----
    hipMemsetAsync(start, 0, (size_t)N * sizeof(int), stream);
    hist_kernel<<<(E + 255) / 256, 256, 0, stream>>>(start, ei, E);
    scan_partial<<<nblk, 256, 0, stream>>>(start, blocksum, N);
    scan_top<<<1, 64, 0, stream>>>(blocksum, nblk, start + N);
    scan_final<<<nblk, 256, 0, stream>>>(start, blocksum, N);
    init_gcur<<<1, 128, 0, stream>>>(gcur, start);
    bin_kernel<<<(E + BIN_CHUNK - 1) / BIN_CHUNK, 256, 0, stream>>>(binned, gcur, ei, E);
    fill2_kernel<<<NB, 256, 0, stream>>>(csr, binned, start, N);

    // ---- conversions / packs ----
    convert_kernel<<<(N * 64 / 4 + 255) / 256, 256, 0, stream>>>(B0, x, N * 64 / 4);
    pack_w_kernel<<<4, 256, 0, stream>>>(wp1, g1w1, 64);
    pack_w_kernel<<<8, 256, 0, stream>>>(wp2, g1w2, 128);
    pack_w_kernel<<<8, 256, 0, stream>>>(wp3, g2w1, 128);
    pack_w_kernel<<<8, 256, 0, stream>>>(wp4, g2w2, 128);
    pack_w_kernel<<<8, 256, 0, stream>>>(wp5, g3w1, 128);
    pack_w_kernel<<<8, 256, 0, stream>>>(wp6, g3w2, 128);
    init_pool_kernel<<<(NGRAPHS * 128 + 255) / 256, 256, 0, stream>>>(pooled);

    const int ggrid = (N + 63) / 64;

    // ---- layer 1 (K=64) ----
    gather_kernel<8><<<(N + 31) / 32, 256, 0, stream>>>(B3, B0, start, csr, N);
    mfma_gemm<64, true><<<ggrid, 256, 0, stream>>>(B3, wp1, g1b1, B1, N);
    mfma_gemm<128, false><<<ggrid, 256, 0, stream>>>(B1, wp2, g1b2, B2, N);   // h1 in B2

    // ---- layer 2 ----
    gather_kernel<16><<<(N + 15) / 16, 256, 0, stream>>>(B1, B2, start, csr, N);
    mfma_gemm<128, true><<<ggrid, 256, 0, stream>>>(B1, wp3, g2b1, B2, N);
    mfma_gemm<128, false><<<ggrid, 256, 0, stream>>>(B2, wp4, g2b2, B1, N);   // h2 in B1

    // ---- layer 3 ----
    gather_kernel<16><<<(N + 15) / 16, 256, 0, stream>>>(B2, B1, start, csr, N);
    mfma_gemm<128, true><<<ggrid, 256, 0, stream>>>(B2, wp5, g3b1, B1, N);
    mfma_gemm<128, false><<<ggrid, 256, 0, stream>>>(B1, wp6, g3b2, B2, N);   // h3 in B2

    // ---- pool + head ----
    pool_kernel<<<(N + 127) / 128, 128, 0, stream>>>(pooled, B2, batch, N);
    head_kernel<<<NGRAPHS, 64, 0, stream>>>(out, pooled, f1w, f1b, f2w, f2b);
}

// Round 5
// 367.191 us; speedup vs baseline: 20.5942x; 1.3381x over previous
//
#include <hip/hip_runtime.h>
#include <hip/hip_bf16.h>
#include <cmath>

#define NNODES 100000
#define NGRAPHS 64
#define SHIFT 10
#define NPB 1024                 // nodes per bucket
#define NB 98                    // ceil(NNODES / NPB)
#define CAP 24576                // max edges per bucket region (exp 16384 +- 128)
#define BIN_CHUNK 4096
#define HSTRIDE 136              // LDS row stride in shorts (272B, 16B-aligned rows)

typedef __attribute__((ext_vector_type(8))) short bf16x8;
typedef __attribute__((ext_vector_type(4))) float f32x4;

__device__ __forceinline__ float bf2f(unsigned short u) {
    unsigned int v = ((unsigned int)u) << 16;
    return __uint_as_float(v);
}
__device__ __forceinline__ unsigned short f2bf(float f) {
    unsigned int v = __float_as_uint(f);
    unsigned int r = (v + 0x7fffu + ((v >> 16) & 1u)) >> 16;
    return (unsigned short)r;
}

__device__ __forceinline__ void atomicMaxF(float* addr, float v) {
    if (v >= 0.f) atomicMax((int*)addr, __float_as_int(v));
    else          atomicMin((unsigned int*)addr, __float_as_uint(v));
}

// ---------------- x (f32) -> bf16 ----------------
__global__ void convert_kernel(unsigned short* __restrict__ dst, const float* __restrict__ src, int n4) {
    int i = blockIdx.x * blockDim.x + threadIdx.x;
    if (i >= n4) return;
    float4 v = ((const float4*)src)[i];
    unsigned short o[4] = { f2bf(v.x), f2bf(v.y), f2bf(v.z), f2bf(v.w) };
    ((uint2*)dst)[i] = *(uint2*)o;
}

// ---------------- CSR build (binned, no global histogram) ----------------
__global__ void init_gcur(int* __restrict__ gcur) {
    int b = threadIdx.x;
    if (b < NB) gcur[b] = b * CAP;
}

// phase 1: block-level counting sort of edges into NB fixed-capacity bucket regions
__global__ __launch_bounds__(256) void bin_kernel(unsigned int* __restrict__ binned,
                                                  int* __restrict__ gcur,
                                                  const int* __restrict__ ei, int E) {
    __shared__ int cnt[NB];
    __shared__ int gbase[NB];
    __shared__ int loff[NB];
    int t = threadIdx.x;
    int base = blockIdx.x * BIN_CHUNK;
    for (int i = t; i < NB; i += 256) { cnt[i] = 0; loff[i] = 0; }
    __syncthreads();
    unsigned int pk[16]; short bk[16]; int ne = 0;
#pragma unroll
    for (int i = 0; i < 16; ++i) {
        int e = base + t + i * 256;
        if (e < E) {
            int s = ei[e], d = ei[E + e];
            int b = d >> SHIFT;
            pk[ne] = ((unsigned int)s << SHIFT) | (unsigned int)(d & (NPB - 1));
            bk[ne] = (short)b;
            ne++;
            atomicAdd(&cnt[b], 1);
        }
    }
    __syncthreads();
    for (int i = t; i < NB; i += 256)
        gbase[i] = cnt[i] ? atomicAdd(&gcur[i], cnt[i]) : 0;
    __syncthreads();
    for (int i = 0; i < ne; ++i) {
        int b = bk[i];
        int pos = atomicAdd(&loff[b], 1);
        binned[gbase[b] + pos] = pk[i];
    }
}

// phase 2: exclusive scan of the 98 bucket counts
__global__ void bucket_scan(int* __restrict__ bbase, const int* __restrict__ gcur) {
    if (threadIdx.x == 0 && blockIdx.x == 0) {
        int acc = 0;
        for (int b = 0; b < NB; ++b) { bbase[b] = acc; acc += gcur[b] - b * CAP; }
        bbase[NB] = acc;
    }
}

// phase 3: one block per bucket: LDS degree histogram + scan -> start[], then csr scatter
__global__ __launch_bounds__(256) void fill2_kernel(int* __restrict__ csr,
                                                    int* __restrict__ start,
                                                    const unsigned int* __restrict__ binned,
                                                    const int* __restrict__ gcur,
                                                    const int* __restrict__ bbase, int N) {
    __shared__ int cur[NPB];
    __shared__ int tsum[256];
    int b = blockIdx.x, t = threadIdx.x;
    int n0 = b << SHIFT;
    int nn = N - n0; if (nn > NPB) nn = NPB;
    int c = gcur[b] - b * CAP;
    int gb = bbase[b];
    const unsigned int* eb = binned + (size_t)b * CAP;
    for (int i = t; i < NPB; i += 256) cur[i] = 0;
    __syncthreads();
    for (int p = t; p < c; p += 256) atomicAdd(&cur[eb[p] & (NPB - 1)], 1);
    __syncthreads();
    int v[4]; int s = 0;
#pragma unroll
    for (int i = 0; i < 4; ++i) { v[i] = cur[t * 4 + i]; s += v[i]; }
    int x = s;
    tsum[t] = x;
    __syncthreads();
    for (int off = 1; off < 256; off <<= 1) {
        int y = (t >= off) ? tsum[t - off] : 0;
        __syncthreads();
        x += y;
        tsum[t] = x;
        __syncthreads();
    }
    int run = x - s + gb;
#pragma unroll
    for (int i = 0; i < 4; ++i) {
        int idx = t * 4 + i;
        cur[idx] = run;
        if (idx < nn) start[n0 + idx] = run;
        run += v[i];
    }
    __syncthreads();
    for (int p = t; p < c; p += 256) {
        unsigned int e = eb[p];
        int slot = atomicAdd(&cur[e & (NPB - 1)], 1);
        csr[slot] = (int)(e >> SHIFT);
    }
    if (t == 0 && b == 0) start[N] = bbase[NB];
}

// ---------------- aggregation (bf16): out[i] = h[i] + sum_j h[j] ----------------
template<int LANES>
__global__ __launch_bounds__(256) void gather_kernel(unsigned short* __restrict__ outb,
                                                     const unsigned short* __restrict__ h,
                                                     const int* __restrict__ start,
                                                     const int* __restrict__ csr, int N) {
    const int D = LANES * 8;
    int t = threadIdx.x;
    int node = blockIdx.x * (256 / LANES) + t / LANES;
    if (node >= N) return;
    int lane = t % LANES;
    float acc[8];
    {
        uint4 v = *(const uint4*)(h + (size_t)node * D + lane * 8);
        const unsigned short* q = (const unsigned short*)&v;
#pragma unroll
        for (int i = 0; i < 8; ++i) acc[i] = bf2f(q[i]);
    }
    int p0 = start[node], p1 = start[node + 1];
    if (p0 < p1) {
        int j = csr[p0];
        for (int p = p0 + 1; p < p1; ++p) {
            int jn = csr[p];
            uint4 v = *(const uint4*)(h + (size_t)j * D + lane * 8);
            const unsigned short* q = (const unsigned short*)&v;
#pragma unroll
            for (int i = 0; i < 8; ++i) acc[i] += bf2f(q[i]);
            j = jn;
        }
        uint4 v = *(const uint4*)(h + (size_t)j * D + lane * 8);
        const unsigned short* q = (const unsigned short*)&v;
#pragma unroll
        for (int i = 0; i < 8; ++i) acc[i] += bf2f(q[i]);
    }
    unsigned short o[8];
#pragma unroll
    for (int i = 0; i < 8; ++i) o[i] = f2bf(acc[i]);
    *(uint4*)(outb + (size_t)node * D + lane * 8) = *(uint4*)o;
}

// ---------------- W (K x 128 f32) -> MFMA B-fragment pack (bf16) ----------------
__global__ void pack_w_kernel(unsigned short* __restrict__ wp, const float* __restrict__ W, int K) {
    int t = blockIdx.x * blockDim.x + threadIdx.x;
    int total = (K / 32) * 8 * 64;
    if (t >= total) return;
    int l = t & 63;
    int n0 = (t >> 6) & 7;
    int kp = t >> 9;
    unsigned short o[8];
#pragma unroll
    for (int j = 0; j < 8; ++j)
        o[j] = f2bf(W[(size_t)(kp * 32 + (l >> 4) * 8 + j) * 128 + n0 * 16 + (l & 15)]);
    *(uint4*)(wp + (size_t)t * 8) = *(uint4*)o;
}

// ---------------- fused MLP: out = (relu(A@W1+b1))@W2 + b2, all M x 128 ----------------
// 256 thr = 4 waves; each wave owns 16 rows end-to-end; intermediate in per-wave LDS tile.
template<int K1>
__global__ __launch_bounds__(256) void mfma_gemm_pair(const unsigned short* __restrict__ A,
                                                      const unsigned short* __restrict__ Wp1,
                                                      const float* __restrict__ bias1,
                                                      const unsigned short* __restrict__ Wp2,
                                                      const float* __restrict__ bias2,
                                                      unsigned short* __restrict__ out, int M) {
    __shared__ unsigned short hl[4][16 * HSTRIDE];
    const int l = threadIdx.x & 63;
    const int w = threadIdx.x >> 6;
    const int mbase = (blockIdx.x * 4 + w) * 16;
    const int kgrp = l >> 4;
    const int col = l & 15;
    int row_a = mbase + col;
    if (row_a >= M) row_a = M - 1;

    f32x4 acc[8];
#pragma unroll
    for (int i = 0; i < 8; ++i) acc[i] = (f32x4){0.f, 0.f, 0.f, 0.f};
#pragma unroll
    for (int kp = 0; kp < K1 / 32; ++kp) {
        bf16x8 a = *(const bf16x8*)(A + (size_t)row_a * K1 + kp * 32 + kgrp * 8);
#pragma unroll
        for (int n0 = 0; n0 < 8; ++n0) {
            bf16x8 bfr = *(const bf16x8*)(Wp1 + ((size_t)(kp * 8 + n0) * 64 + l) * 8);
            acc[n0] = __builtin_amdgcn_mfma_f32_16x16x32_bf16(a, bfr, acc[n0], 0, 0, 0);
        }
    }

    unsigned short* hb = hl[w];
#pragma unroll
    for (int n0 = 0; n0 < 8; ++n0) {
        float bv = bias1[n0 * 16 + col];
#pragma unroll
        for (int r = 0; r < 4; ++r) {
            float v = acc[n0][r] + bv;
            v = fmaxf(v, 0.f);
            hb[(kgrp * 4 + r) * HSTRIDE + n0 * 16 + col] = f2bf(v);
        }
    }
    __syncthreads();

    f32x4 acc2[8];
#pragma unroll
    for (int i = 0; i < 8; ++i) acc2[i] = (f32x4){0.f, 0.f, 0.f, 0.f};
#pragma unroll
    for (int kp = 0; kp < 4; ++kp) {
        bf16x8 a2 = *(const bf16x8*)(hb + col * HSTRIDE + kp * 32 + kgrp * 8);
#pragma unroll
        for (int n0 = 0; n0 < 8; ++n0) {
            bf16x8 bfr = *(const bf16x8*)(Wp2 + ((size_t)(kp * 8 + n0) * 64 + l) * 8);
            acc2[n0] = __builtin_amdgcn_mfma_f32_16x16x32_bf16(a2, bfr, acc2[n0], 0, 0, 0);
        }
    }

#pragma unroll
    for (int n0 = 0; n0 < 8; ++n0) {
        float bv = bias2[n0 * 16 + col];
#pragma unroll
        for (int r = 0; r < 4; ++r) {
            int row = mbase + kgrp * 4 + r;
            if (row < M)
                out[(size_t)row * 128 + n0 * 16 + col] = f2bf(acc2[n0][r] + bv);
        }
    }
}

// ---------------- pool + head ----------------
__global__ void init_pool_kernel(float* p) {
    int i = blockIdx.x * blockDim.x + threadIdx.x;
    if (i < NGRAPHS * 128) p[i] = -INFINITY;
}

__global__ __launch_bounds__(128) void pool_kernel(float* __restrict__ pooled,
                                                   const unsigned short* __restrict__ h,
                                                   const int* __restrict__ batch, int N) {
    const int f = threadIdx.x;
    int n0 = blockIdx.x * 128;
    int n1 = n0 + 128;
    if (n1 > N) n1 = N;
    int cur = -1;
    float run = -INFINITY;
    for (int n = n0; n < n1; ++n) {
        int g = batch[n];
        if (g != cur) {
            if (cur >= 0) atomicMaxF(&pooled[cur * 128 + f], run);
            cur = g;
            run = -INFINITY;
        }
        run = fmaxf(run, bf2f(h[(size_t)n * 128 + f]));
    }
    if (cur >= 0) atomicMaxF(&pooled[cur * 128 + f], run);
}

__global__ __launch_bounds__(64) void head_kernel(float* __restrict__ out,
                                                  const float* __restrict__ pooled,
                                                  const float* __restrict__ w1,
                                                  const float* __restrict__ b1,
                                                  const float* __restrict__ w2,
                                                  const float* __restrict__ b2) {
    int g = blockIdx.x, t = threadIdx.x;
    __shared__ float a[64];
    __shared__ float o[10];
    __shared__ float red[2];
    const float* pg = pooled + g * 128;
    float acc = b1[t];
    for (int k = 0; k < 128; ++k) acc = fmaf(pg[k], w1[k * 64 + t], acc);
    a[t] = fmaxf(acc, 0.f);
    __syncthreads();
    if (t < 10) {
        float s = b2[t];
        for (int k = 0; k < 64; ++k) s = fmaf(a[k], w2[k * 10 + t], s);
        o[t] = s;
    }
    __syncthreads();
    if (t == 0) {
        float m = -INFINITY;
        for (int c = 0; c < 10; ++c) m = fmaxf(m, o[c]);
        float se = 0.f;
        for (int c = 0; c < 10; ++c) se += expf(o[c] - m);
        red[0] = m;
        red[1] = logf(se);
    }
    __syncthreads();
    if (t < 10) out[g * 10 + t] = o[t] - red[0] - red[1];
}

extern "C" void kernel_launch(void* const* d_in, const int* in_sizes, int n_in,
                              void* d_out, int out_size, void* d_ws, size_t ws_size,
                              hipStream_t stream) {
    const float* x    = (const float*)d_in[0];
    const int* ei     = (const int*)d_in[1];
    const int* batch  = (const int*)d_in[2];
    const float* g1w1 = (const float*)d_in[3];  const float* g1b1 = (const float*)d_in[4];
    const float* g1w2 = (const float*)d_in[5];  const float* g1b2 = (const float*)d_in[6];
    const float* g2w1 = (const float*)d_in[7];  const float* g2b1 = (const float*)d_in[8];
    const float* g2w2 = (const float*)d_in[9];  const float* g2b2 = (const float*)d_in[10];
    const float* g3w1 = (const float*)d_in[11]; const float* g3b1 = (const float*)d_in[12];
    const float* g3w2 = (const float*)d_in[13]; const float* g3b2 = (const float*)d_in[14];
    const float* f1w  = (const float*)d_in[15]; const float* f1b  = (const float*)d_in[16];
    const float* f2w  = (const float*)d_in[17]; const float* f2b  = (const float*)d_in[18];
    float* out = (float*)d_out;

    const int N = NNODES;
    const int E = in_sizes[1] / 2;

    char* base = (char*)d_ws;
    auto alloc = [&](size_t bytes) { char* p = base; base += (bytes + 255) & ~(size_t)255; return p; };

    unsigned short* B1 = (unsigned short*)alloc((size_t)N * 128 * 2);
    unsigned short* B2 = (unsigned short*)alloc((size_t)N * 128 * 2);
    unsigned short* B0 = (unsigned short*)alloc((size_t)N * 64 * 2);   // x bf16
    // B3 (layer-1 gather out, N*64*2 = 12.8MB) aliases binned (NB*CAP*4 = 9.63MB):
    // binned is dead before B3's first write.
    char* shared_region = alloc((size_t)N * 64 * 2);
    unsigned short* B3 = (unsigned short*)shared_region;
    unsigned int* binned = (unsigned int*)shared_region;
    int* csr      = (int*)alloc((size_t)E * 4);
    int* start    = (int*)alloc((size_t)(N + 1) * 4);
    int* gcur     = (int*)alloc((size_t)(NB + 4) * 4);
    int* bbase    = (int*)alloc((size_t)(NB + 4) * 4);
    float* pooled = (float*)alloc((size_t)NGRAPHS * 128 * 4);
    unsigned short* wp1 = (unsigned short*)alloc((size_t)64 * 128 * 2);
    unsigned short* wp2 = (unsigned short*)alloc((size_t)128 * 128 * 2);
    unsigned short* wp3 = (unsigned short*)alloc((size_t)128 * 128 * 2);
    unsigned short* wp4 = (unsigned short*)alloc((size_t)128 * 128 * 2);
    unsigned short* wp5 = (unsigned short*)alloc((size_t)128 * 128 * 2);
    unsigned short* wp6 = (unsigned short*)alloc((size_t)128 * 128 * 2);

    // ---- CSR build (no global histogram) ----
    init_gcur<<<1, 128, 0, stream>>>(gcur);
    bin_kernel<<<(E + BIN_CHUNK - 1) / BIN_CHUNK, 256, 0, stream>>>(binned, gcur, ei, E);
    bucket_scan<<<1, 64, 0, stream>>>(bbase, gcur);
    fill2_kernel<<<NB, 256, 0, stream>>>(csr, start, binned, gcur, bbase, N);

    // ---- conversions / packs ----
    convert_kernel<<<(N * 64 / 4 + 255) / 256, 256, 0, stream>>>(B0, x, N * 64 / 4);
    pack_w_kernel<<<4, 256, 0, stream>>>(wp1, g1w1, 64);
    pack_w_kernel<<<8, 256, 0, stream>>>(wp2, g1w2, 128);
    pack_w_kernel<<<8, 256, 0, stream>>>(wp3, g2w1, 128);
    pack_w_kernel<<<8, 256, 0, stream>>>(wp4, g2w2, 128);
    pack_w_kernel<<<8, 256, 0, stream>>>(wp5, g3w1, 128);
    pack_w_kernel<<<8, 256, 0, stream>>>(wp6, g3w2, 128);
    init_pool_kernel<<<(NGRAPHS * 128 + 255) / 256, 256, 0, stream>>>(pooled);

    const int pgrid = (N + 63) / 64;

    // ---- layer 1 (K=64) ----  (gather1 writes B3 only after fill2 consumed binned)
    gather_kernel<8><<<(N + 31) / 32, 256, 0, stream>>>(B3, B0, start, csr, N);
    mfma_gemm_pair<64><<<pgrid, 256, 0, stream>>>(B3, wp1, g1b1, wp2, g1b2, B1, N);

    // ---- layer 2 ----
    gather_kernel<16><<<(N + 15) / 16, 256, 0, stream>>>(B2, B1, start, csr, N);
    mfma_gemm_pair<128><<<pgrid, 256, 0, stream>>>(B2, wp3, g2b1, wp4, g2b2, B1, N);

    // ---- layer 3 ----
    gather_kernel<16><<<(N + 15) / 16, 256, 0, stream>>>(B2, B1, start, csr, N);
    mfma_gemm_pair<128><<<pgrid, 256, 0, stream>>>(B2, wp5, g3b1, wp6, g3b2, B1, N);

    // ---- pool + head ----
    pool_kernel<<<(N + 127) / 128, 128, 0, stream>>>(pooled, B1, batch, N);
    head_kernel<<<NGRAPHS, 64, 0, stream>>>(out, pooled, f1w, f1b, f2w, f2b);
}